// Round 1
// baseline (477.774 us; speedup 1.0000x reference)
//
#include <hip/hip_runtime.h>
#include <hip/hip_bf16.h>

#define S_LEN 2048
#define D_DIM 128
#define QBLK 64
#define KBLK 64
#define NSTEP (S_LEN / KBLK)   // 32

typedef __bf16 bf16x8 __attribute__((ext_vector_type(8)));
typedef float  f32x4  __attribute__((ext_vector_type(4)));

// RNE fp32 -> bf16 (bit pattern as ushort)
__device__ __forceinline__ unsigned short f2bf(float f) {
    unsigned int u = __float_as_uint(f);
    u += 0x7fffu + ((u >> 16) & 1u);
    return (unsigned short)(u >> 16);
}

__global__ __launch_bounds__(256, 2)
void attn_fwd(const float* __restrict__ Q, const float* __restrict__ K,
              const float* __restrict__ V, float* __restrict__ O) {
    // LDS: K tile [64][128] bf16 (swizzled), V tile transposed [128][64] bf16 (swizzled),
    // P per-wave [16][64] bf16 (swizzled). 16KB + 16KB + 8KB = 40KB.
    __shared__ unsigned short k_lds[QBLK * D_DIM];
    __shared__ unsigned short v_lds[D_DIM * KBLK];
    __shared__ unsigned short p_lds[4 * 16 * KBLK];

    const int tid = threadIdx.x;
    const int w   = tid >> 6;     // wave 0..3
    const int l   = tid & 63;     // lane
    const int g   = l >> 4;       // 16-lane group 0..3
    const int lr  = l & 15;

    const int bh    = blockIdx.x >> 5;      // head index 0..63 (b*16+h)
    const int qt    = blockIdx.x & 31;      // q tile 0..31
    const size_t base  = (size_t)bh * S_LEN * D_DIM;
    const int    qbase = qt * QBLK;

    // ---------------- stage Q tile (fp32 -> bf16) into k_lds ----------------
    {
        const float* qp = Q + base + (size_t)qbase * D_DIM;
        #pragma unroll
        for (int i = 0; i < 4; ++i) {
            int c    = tid + i * 256;       // chunk 0..1023
            int row  = c >> 4;              // 0..63
            int col8 = c & 15;              // 0..15 (8-elem chunks)
            const float* src = qp + row * D_DIM + col8 * 8;
            float4 a = *(const float4*)src;
            float4 b = *(const float4*)(src + 4);
            unsigned short pk[8];
            pk[0] = f2bf(a.x); pk[1] = f2bf(a.y); pk[2] = f2bf(a.z); pk[3] = f2bf(a.w);
            pk[4] = f2bf(b.x); pk[5] = f2bf(b.y); pk[6] = f2bf(b.z); pk[7] = f2bf(b.w);
            int idx = (row * 128 + col8 * 8) ^ ((row & 7) << 3);
            #pragma unroll
            for (int j = 0; j < 8; ++j) k_lds[idx + j] = pk[j];  // contiguous, compiler packs
        }
    }
    __syncthreads();

    // ---------------- Q fragments into registers (A-layout) ----------------
    bf16x8 qf[4];
    {
        int row = w * 16 + lr;
        #pragma unroll
        for (int kt = 0; kt < 4; ++kt) {
            int d0 = kt * 32 + g * 8;
            int idx = (row * 128 + d0) ^ ((row & 7) << 3);
            qf[kt] = *(const bf16x8*)&k_lds[idx];
        }
    }

    // ---------------- accumulators / online softmax state ----------------
    f32x4 o[8];
    #pragma unroll
    for (int dt = 0; dt < 8; ++dt) o[dt] = (f32x4){0.f, 0.f, 0.f, 0.f};
    float m[4], lsum[4];
    #pragma unroll
    for (int r = 0; r < 4; ++r) { m[r] = -INFINITY; lsum[r] = 0.f; }

    const float* kp = K + base;
    const float* vp = V + base;
    const float  scale = 0.08838834764831845f;   // 1/sqrt(128)
    const float  L2E   = 1.4426950408889634f;

    for (int t = 0; t < NSTEP; ++t) {
        __syncthreads();   // previous iteration's LDS reads done

        // ---- stage K tile: row-major [kv][d], bf16, swizzled ----
        const float* ks = kp + (size_t)t * KBLK * D_DIM;
        #pragma unroll
        for (int i = 0; i < 4; ++i) {
            int c    = tid + i * 256;
            int row  = c >> 4;
            int col8 = c & 15;
            const float* src = ks + row * D_DIM + col8 * 8;
            float4 a = *(const float4*)src;
            float4 b = *(const float4*)(src + 4);
            unsigned short pk[8];
            pk[0] = f2bf(a.x); pk[1] = f2bf(a.y); pk[2] = f2bf(a.z); pk[3] = f2bf(a.w);
            pk[4] = f2bf(b.x); pk[5] = f2bf(b.y); pk[6] = f2bf(b.z); pk[7] = f2bf(b.w);
            int idx = (row * 128 + col8 * 8) ^ ((row & 7) << 3);
            #pragma unroll
            for (int j = 0; j < 8; ++j) k_lds[idx + j] = pk[j];
        }

        // ---- stage V tile TRANSPOSED: [d][kv], bf16, swizzled ----
        const float* vs = vp + (size_t)t * KBLK * D_DIM;
        {
            int dq   = (tid & 7) + ((tid >> 6) & 3) * 8;   // 0..31 (d quad)
            int kvpl = (tid >> 3) & 7;
            #pragma unroll
            for (int i = 0; i < 4; ++i) {
                int kvp = kvpl + i * 8;                    // 0..31 (kv pair)
                const float* s0 = vs + (2 * kvp) * D_DIM + dq * 4;
                float4 r0 = *(const float4*)s0;
                float4 r1 = *(const float4*)(s0 + D_DIM);
                #pragma unroll
                for (int wv = 0; wv < 4; ++wv) {
                    int d = dq * 4 + wv;
                    unsigned int pk = (unsigned int)f2bf(((const float*)&r0)[wv])
                                    | ((unsigned int)f2bf(((const float*)&r1)[wv]) << 16);
                    int idx = (d * 64 + 2 * kvp) ^ ((d & 7) << 3);
                    *(unsigned int*)&v_lds[idx] = pk;
                }
            }
        }
        __syncthreads();

        // ---- S = Q K^T  (per wave: 16 rows x 64 cols) ----
        f32x4 sacc[4];
        #pragma unroll
        for (int ct = 0; ct < 4; ++ct) sacc[ct] = (f32x4){0.f, 0.f, 0.f, 0.f};
        #pragma unroll
        for (int kt = 0; kt < 4; ++kt) {
            #pragma unroll
            for (int ct = 0; ct < 4; ++ct) {
                int kv = ct * 16 + lr;
                int d0 = kt * 32 + g * 8;
                int idx = (kv * 128 + d0) ^ ((kv & 7) << 3);
                bf16x8 kf = *(const bf16x8*)&k_lds[idx];
                sacc[ct] = __builtin_amdgcn_mfma_f32_16x16x32_bf16(qf[kt], kf, sacc[ct], 0, 0, 0);
            }
        }

        // ---- online softmax (rows owned by 16-lane groups) ----
        float pv[4][4];   // [ct][r]
        float mt[4];
        #pragma unroll
        for (int r = 0; r < 4; ++r) mt[r] = -INFINITY;
        #pragma unroll
        for (int ct = 0; ct < 4; ++ct) {
            #pragma unroll
            for (int r = 0; r < 4; ++r) {
                float x = sacc[ct][r] * scale;
                x = (x == 0.0f) ? -1e9f : x;     // value-dependent mask from reference
                pv[ct][r] = x;
                mt[r] = fmaxf(mt[r], x);
            }
        }
        #pragma unroll
        for (int r = 0; r < 4; ++r) {
            #pragma unroll
            for (int msk = 1; msk <= 8; msk <<= 1)
                mt[r] = fmaxf(mt[r], __shfl_xor(mt[r], msk));
        }
        float corr[4], rs[4];
        #pragma unroll
        for (int r = 0; r < 4; ++r) {
            float mn = fmaxf(m[r], mt[r]);
            corr[r] = exp2f((m[r] - mn) * L2E);
            m[r] = mn;
            rs[r] = 0.f;
        }
        #pragma unroll
        for (int ct = 0; ct < 4; ++ct) {
            #pragma unroll
            for (int r = 0; r < 4; ++r) {
                float e = exp2f((pv[ct][r] - m[r]) * L2E);
                pv[ct][r] = e;
                rs[r] += e;
            }
        }
        #pragma unroll
        for (int r = 0; r < 4; ++r) {
            #pragma unroll
            for (int msk = 1; msk <= 8; msk <<= 1)
                rs[r] += __shfl_xor(rs[r], msk);
            lsum[r] = lsum[r] * corr[r] + rs[r];
        }
        #pragma unroll
        for (int dt = 0; dt < 8; ++dt) {
            #pragma unroll
            for (int r = 0; r < 4; ++r) o[dt][r] *= corr[r];
        }

        // ---- P -> bf16 -> per-wave LDS (C-layout -> A-layout transpose) ----
        unsigned short* pw = p_lds + w * (16 * KBLK);
        #pragma unroll
        for (int ct = 0; ct < 4; ++ct) {
            #pragma unroll
            for (int r = 0; r < 4; ++r) {
                int qr = g * 4 + r;
                int kv = ct * 16 + lr;
                int idx = (qr * 64 + kv) ^ ((qr & 7) << 3);
                pw[idx] = f2bf(pv[ct][r]);
            }
        }
        // same-wave LDS write->read: compiler inserts lgkmcnt

        // ---- O += P V ----
        #pragma unroll
        for (int kt2 = 0; kt2 < 2; ++kt2) {
            int kv0 = kt2 * 32 + g * 8;
            int idxp = (lr * 64 + kv0) ^ ((lr & 7) << 3);
            bf16x8 pa = *(const bf16x8*)&pw[idxp];
            #pragma unroll
            for (int dt = 0; dt < 8; ++dt) {
                int d = dt * 16 + lr;
                int idxv = (d * 64 + kv0) ^ ((d & 7) << 3);
                bf16x8 vb = *(const bf16x8*)&v_lds[idxv];
                o[dt] = __builtin_amdgcn_mfma_f32_16x16x32_bf16(pa, vb, o[dt], 0, 0, 0);
            }
        }
    }

    // ---------------- epilogue: O /= l, store fp32 ----------------
    float* op = O + base + (size_t)qbase * D_DIM;
    #pragma unroll
    for (int r = 0; r < 4; ++r) {
        float inv = 1.0f / lsum[r];
        int row = w * 16 + g * 4 + r;
        #pragma unroll
        for (int dt = 0; dt < 8; ++dt) {
            op[row * D_DIM + dt * 16 + lr] = o[dt][r] * inv;
        }
    }
}

extern "C" void kernel_launch(void* const* d_in, const int* in_sizes, int n_in,
                              void* d_out, int out_size, void* d_ws, size_t ws_size,
                              hipStream_t stream) {
    const float* q = (const float*)d_in[0];
    const float* k = (const float*)d_in[1];
    const float* v = (const float*)d_in[2];
    float* out = (float*)d_out;
    dim3 grid(64 * (S_LEN / QBLK));   // 64 heads * 32 q-tiles = 2048 blocks
    dim3 block(256);
    hipLaunchKernelGGL(attn_fwd, grid, block, 0, stream, q, k, v, out);
}

// Round 2
// 400.849 us; speedup vs baseline: 1.1919x; 1.1919x over previous
//
#include <hip/hip_runtime.h>
#include <hip/hip_bf16.h>

#define S_LEN 2048
#define D_DIM 128
#define QBLK 64
#define KBLK 64
#define NSTEP (S_LEN / KBLK)   // 32
#define NBH 64                 // B*H

typedef __bf16 bf16x8 __attribute__((ext_vector_type(8)));
typedef float  f32x4  __attribute__((ext_vector_type(4)));
typedef unsigned short u16x8 __attribute__((ext_vector_type(8)));

// RNE fp32 -> bf16 (bit pattern as ushort)
__device__ __forceinline__ unsigned short f2bf(float f) {
    unsigned int u = __float_as_uint(f);
    u += 0x7fffu + ((u >> 16) & 1u);
    return (unsigned short)(u >> 16);
}

__device__ __forceinline__ void gload_lds16(const void* g, void* l) {
    __builtin_amdgcn_global_load_lds(
        (const __attribute__((address_space(1))) unsigned int*)g,
        (__attribute__((address_space(3))) unsigned int*)l, 16, 0, 0);
}

__device__ __forceinline__ void block_sync() {
    asm volatile("" ::: "memory");
    __builtin_amdgcn_s_barrier();
    asm volatile("" ::: "memory");
}

// ---------------- prepass: K fp32 -> bf16 (same layout) ----------------
__global__ __launch_bounds__(256)
void conv_k(const float* __restrict__ in, unsigned short* __restrict__ out) {
    const int n8 = (NBH * S_LEN * D_DIM) / 8;
    for (int c = blockIdx.x * blockDim.x + threadIdx.x; c < n8; c += gridDim.x * blockDim.x) {
        const float* s = in + (size_t)c * 8;
        float4 a = *(const float4*)s;
        float4 b = *(const float4*)(s + 4);
        u16x8 v;
        v[0] = f2bf(a.x); v[1] = f2bf(a.y); v[2] = f2bf(a.z); v[3] = f2bf(a.w);
        v[4] = f2bf(b.x); v[5] = f2bf(b.y); v[6] = f2bf(b.z); v[7] = f2bf(b.w);
        *(u16x8*)(out + (size_t)c * 8) = v;
    }
}

// ---------------- prepass: V fp32 [bh][s][d] -> bf16 transposed [bh][d][s] ----------------
__global__ __launch_bounds__(256)
void conv_vt(const float* __restrict__ V, unsigned short* __restrict__ Vt) {
    __shared__ unsigned short tl[64][72];   // 64x64 tile, padded stride
    const int b  = blockIdx.x;
    const int dt = b & 1;
    const int st = (b >> 1) & 31;
    const int bh = b >> 6;
    const float* src = V + (size_t)bh * S_LEN * D_DIM + (size_t)(st * 64) * D_DIM + dt * 64;
    #pragma unroll
    for (int i = 0; i < 4; ++i) {
        int c = threadIdx.x + i * 256;   // 64 rows x 16 float4 cols
        int r = c >> 4, c4 = c & 15;
        float4 x = *(const float4*)(src + r * D_DIM + c4 * 4);
        tl[r][c4 * 4 + 0] = f2bf(x.x);
        tl[r][c4 * 4 + 1] = f2bf(x.y);
        tl[r][c4 * 4 + 2] = f2bf(x.z);
        tl[r][c4 * 4 + 3] = f2bf(x.w);
    }
    __syncthreads();
    unsigned short* dst = Vt + (size_t)bh * D_DIM * S_LEN + (size_t)(dt * 64) * S_LEN + st * 64;
    #pragma unroll
    for (int i = 0; i < 2; ++i) {
        int c  = threadIdx.x + i * 256;  // 64 d-rows x 8 chunks of 8
        int dl = c >> 3, s0 = (c & 7) * 8;
        u16x8 v;
        #pragma unroll
        for (int j = 0; j < 8; ++j) v[j] = tl[s0 + j][dl];
        *(u16x8*)(dst + (size_t)dl * S_LEN + s0) = v;
    }
}

// ---------------- main: bf16-staged, gload_lds, counted-vmcnt pipeline ----------------
__global__ __launch_bounds__(256, 2)
void attn_fwd_bf(const float* __restrict__ Q, const unsigned short* __restrict__ Kb,
                 const unsigned short* __restrict__ Vt, float* __restrict__ O) {
    // LDS: K dbuf 2x16KB, V 16KB, P 8KB = 56KB
    __shared__ unsigned short k_lds[2][QBLK * D_DIM];
    __shared__ unsigned short v_lds[D_DIM * KBLK];
    __shared__ unsigned short p_lds[4 * 16 * KBLK];

    const int tid = threadIdx.x;
    const int w   = tid >> 6;
    const int l   = tid & 63;
    const int g   = l >> 4;
    const int lr  = l & 15;

    const int bh    = blockIdx.x >> 5;
    const int qt    = blockIdx.x & 31;
    const size_t base  = (size_t)bh * S_LEN * D_DIM;
    const int    qbase = qt * QBLK;

    // ---- Q fragments direct from fp32 global (once) ----
    bf16x8 qf[4];
    {
        const float* qp = Q + base + (size_t)(qbase + w * 16 + lr) * D_DIM;
        #pragma unroll
        for (int kt = 0; kt < 4; ++kt) {
            const float* s = qp + kt * 32 + g * 8;
            float4 a = *(const float4*)s;
            float4 b = *(const float4*)(s + 4);
            unsigned short pk[8];
            pk[0] = f2bf(a.x); pk[1] = f2bf(a.y); pk[2] = f2bf(a.z); pk[3] = f2bf(a.w);
            pk[4] = f2bf(b.x); pk[5] = f2bf(b.y); pk[6] = f2bf(b.z); pk[7] = f2bf(b.w);
            qf[kt] = *(const bf16x8*)pk;
        }
    }

    // ---- per-lane staging source addresses (inverse-swizzled) ----
    const int seg = w * 4;
    const char* kgp[4];
    const char* vgp[4];
    {
        const char* kbase = (const char*)Kb + base * 2;
        const char* vbase = (const char*)Vt + base * 2;
        #pragma unroll
        for (int i = 0; i < 4; ++i) {
            int kr = (seg + i) * 4 + (l >> 4);                 // kv row 0..63
            int kc = ((l & 15) * 8) ^ ((kr & 7) << 3);         // d col (inverse swizzle)
            kgp[i] = kbase + kr * (D_DIM * 2) + kc * 2;
            int vd = (seg + i) * 8 + (l >> 3);                 // d row 0..127
            int vk = ((l & 7) * 8) ^ ((vd & 7) << 3);          // kv col (inverse swizzle)
            vgp[i] = vbase + (size_t)vd * (S_LEN * 2) + vk * 2;
        }
    }

    // ---- accumulators / softmax state ----
    f32x4 o[8];
    #pragma unroll
    for (int dt = 0; dt < 8; ++dt) o[dt] = (f32x4){0.f, 0.f, 0.f, 0.f};
    float m[4], lsum[4];
    #pragma unroll
    for (int r = 0; r < 4; ++r) { m[r] = -INFINITY; lsum[r] = 0.f; }

    const float scale = 0.08838834764831845f;   // 1/sqrt(128)
    const float L2E   = 1.4426950408889634f;

    // ---- prologue: issue K(0) ----
    #pragma unroll
    for (int i = 0; i < 4; ++i) {
        gload_lds16(kgp[i], &k_lds[0][(seg + i) * 512]);
        kgp[i] += KBLK * D_DIM * 2;
    }

    int cur = 0;
    #pragma unroll 1
    for (int t = 0; t < NSTEP; ++t) {
        // issue V(t) into single V buffer
        #pragma unroll
        for (int i = 0; i < 4; ++i) {
            gload_lds16(vgp[i], &v_lds[(seg + i) * 512]);
            vgp[i] += KBLK * 2;
        }
        if (t < NSTEP - 1) {
            // issue K(t+1) into other K buffer
            #pragma unroll
            for (int i = 0; i < 4; ++i) {
                gload_lds16(kgp[i], &k_lds[cur ^ 1][(seg + i) * 512]);
                kgp[i] += KBLK * D_DIM * 2;
            }
            asm volatile("s_waitcnt vmcnt(8)" ::: "memory");   // K(t) landed
        } else {
            asm volatile("s_waitcnt vmcnt(4)" ::: "memory");   // K(t) landed
        }
        block_sync();

        // ---- S = Q K^T ----
        const unsigned short* kb = k_lds[cur];
        f32x4 sacc[4];
        #pragma unroll
        for (int ct = 0; ct < 4; ++ct) sacc[ct] = (f32x4){0.f, 0.f, 0.f, 0.f};
        #pragma unroll
        for (int kt = 0; kt < 4; ++kt) {
            #pragma unroll
            for (int ct = 0; ct < 4; ++ct) {
                int kv = ct * 16 + lr;
                int d0 = kt * 32 + g * 8;
                int idx = (kv * 128 + d0) ^ ((kv & 7) << 3);
                bf16x8 kf = *(const bf16x8*)&kb[idx];
                sacc[ct] = __builtin_amdgcn_mfma_f32_16x16x32_bf16(qf[kt], kf, sacc[ct], 0, 0, 0);
            }
        }

        // ---- online softmax ----
        float pv[4][4];
        float mt[4];
        #pragma unroll
        for (int r = 0; r < 4; ++r) mt[r] = -INFINITY;
        #pragma unroll
        for (int ct = 0; ct < 4; ++ct) {
            #pragma unroll
            for (int r = 0; r < 4; ++r) {
                float x = sacc[ct][r] * scale;
                x = (x == 0.0f) ? -1e9f : x;     // value-dependent mask from reference
                pv[ct][r] = x;
                mt[r] = fmaxf(mt[r], x);
            }
        }
        #pragma unroll
        for (int r = 0; r < 4; ++r) {
            #pragma unroll
            for (int msk = 1; msk <= 8; msk <<= 1)
                mt[r] = fmaxf(mt[r], __shfl_xor(mt[r], msk));
        }
        float corr[4], rs[4];
        #pragma unroll
        for (int r = 0; r < 4; ++r) {
            float mn = fmaxf(m[r], mt[r]);
            corr[r] = exp2f((m[r] - mn) * L2E);
            m[r] = mn;
            rs[r] = 0.f;
        }
        #pragma unroll
        for (int ct = 0; ct < 4; ++ct) {
            #pragma unroll
            for (int r = 0; r < 4; ++r) {
                float e = exp2f((pv[ct][r] - m[r]) * L2E);
                pv[ct][r] = e;
                rs[r] += e;
            }
        }
        #pragma unroll
        for (int r = 0; r < 4; ++r) {
            #pragma unroll
            for (int msk = 1; msk <= 8; msk <<= 1)
                rs[r] += __shfl_xor(rs[r], msk);
            lsum[r] = lsum[r] * corr[r] + rs[r];
        }
        #pragma unroll
        for (int dt = 0; dt < 8; ++dt) {
            #pragma unroll
            for (int r = 0; r < 4; ++r) o[dt][r] *= corr[r];
        }

        if (t < NSTEP - 1) asm volatile("s_waitcnt vmcnt(4)" ::: "memory");  // V(t) landed
        else               asm volatile("s_waitcnt vmcnt(0)" ::: "memory");
        block_sync();

        // ---- P -> bf16 -> per-wave LDS ----
        unsigned short* pw = p_lds + w * (16 * KBLK);
        #pragma unroll
        for (int ct = 0; ct < 4; ++ct) {
            #pragma unroll
            for (int r = 0; r < 4; ++r) {
                int qr = g * 4 + r;
                int kv = ct * 16 + lr;
                int idx = (qr * 64 + kv) ^ ((qr & 7) << 3);
                pw[idx] = f2bf(pv[ct][r]);
            }
        }

        // ---- O += P V ----
        #pragma unroll
        for (int kt2 = 0; kt2 < 2; ++kt2) {
            int kv0 = kt2 * 32 + g * 8;
            int idxp = (lr * 64 + kv0) ^ ((lr & 7) << 3);
            bf16x8 pa = *(const bf16x8*)&pw[idxp];
            #pragma unroll
            for (int dt = 0; dt < 8; ++dt) {
                int d = dt * 16 + lr;
                int idxv = (d * 64 + kv0) ^ ((d & 7) << 3);
                bf16x8 vb = *(const bf16x8*)&v_lds[idxv];
                o[dt] = __builtin_amdgcn_mfma_f32_16x16x32_bf16(pa, vb, o[dt], 0, 0, 0);
            }
        }

        block_sync();   // PV reads done before next iter's V/K stage overwrites
        cur ^= 1;
    }

    // ---- epilogue ----
    float* op = O + base + (size_t)qbase * D_DIM;
    #pragma unroll
    for (int r = 0; r < 4; ++r) {
        float inv = 1.0f / lsum[r];
        int row = w * 16 + g * 4 + r;
        #pragma unroll
        for (int dt = 0; dt < 8; ++dt) {
            op[row * D_DIM + dt * 16 + lr] = o[dt][r] * inv;
        }
    }
}

// ---------------- fallback (round-1 kernel, fp32-staged) ----------------
__global__ __launch_bounds__(256, 2)
void attn_fwd_f32(const float* __restrict__ Q, const float* __restrict__ K,
                  const float* __restrict__ V, float* __restrict__ O) {
    __shared__ unsigned short k_lds[QBLK * D_DIM];
    __shared__ unsigned short v_lds[D_DIM * KBLK];
    __shared__ unsigned short p_lds[4 * 16 * KBLK];

    const int tid = threadIdx.x;
    const int w   = tid >> 6;
    const int l   = tid & 63;
    const int g   = l >> 4;
    const int lr  = l & 15;

    const int bh    = blockIdx.x >> 5;
    const int qt    = blockIdx.x & 31;
    const size_t base  = (size_t)bh * S_LEN * D_DIM;
    const int    qbase = qt * QBLK;

    {
        const float* qp = Q + base + (size_t)qbase * D_DIM;
        #pragma unroll
        for (int i = 0; i < 4; ++i) {
            int c    = tid + i * 256;
            int row  = c >> 4;
            int col8 = c & 15;
            const float* src = qp + row * D_DIM + col8 * 8;
            float4 a = *(const float4*)src;
            float4 b = *(const float4*)(src + 4);
            unsigned short pk[8];
            pk[0] = f2bf(a.x); pk[1] = f2bf(a.y); pk[2] = f2bf(a.z); pk[3] = f2bf(a.w);
            pk[4] = f2bf(b.x); pk[5] = f2bf(b.y); pk[6] = f2bf(b.z); pk[7] = f2bf(b.w);
            int idx = (row * 128 + col8 * 8) ^ ((row & 7) << 3);
            #pragma unroll
            for (int j = 0; j < 8; ++j) k_lds[idx + j] = pk[j];
        }
    }
    __syncthreads();

    bf16x8 qf[4];
    {
        int row = w * 16 + lr;
        #pragma unroll
        for (int kt = 0; kt < 4; ++kt) {
            int d0 = kt * 32 + g * 8;
            int idx = (row * 128 + d0) ^ ((row & 7) << 3);
            qf[kt] = *(const bf16x8*)&k_lds[idx];
        }
    }

    f32x4 o[8];
    #pragma unroll
    for (int dt = 0; dt < 8; ++dt) o[dt] = (f32x4){0.f, 0.f, 0.f, 0.f};
    float m[4], lsum[4];
    #pragma unroll
    for (int r = 0; r < 4; ++r) { m[r] = -INFINITY; lsum[r] = 0.f; }

    const float* kp = K + base;
    const float* vp = V + base;
    const float  scale = 0.08838834764831845f;
    const float  L2E   = 1.4426950408889634f;

    for (int t = 0; t < NSTEP; ++t) {
        __syncthreads();

        const float* ks = kp + (size_t)t * KBLK * D_DIM;
        #pragma unroll
        for (int i = 0; i < 4; ++i) {
            int c    = tid + i * 256;
            int row  = c >> 4;
            int col8 = c & 15;
            const float* src = ks + row * D_DIM + col8 * 8;
            float4 a = *(const float4*)src;
            float4 b = *(const float4*)(src + 4);
            unsigned short pk[8];
            pk[0] = f2bf(a.x); pk[1] = f2bf(a.y); pk[2] = f2bf(a.z); pk[3] = f2bf(a.w);
            pk[4] = f2bf(b.x); pk[5] = f2bf(b.y); pk[6] = f2bf(b.z); pk[7] = f2bf(b.w);
            int idx = (row * 128 + col8 * 8) ^ ((row & 7) << 3);
            #pragma unroll
            for (int j = 0; j < 8; ++j) k_lds[idx + j] = pk[j];
        }

        const float* vs = vp + (size_t)t * KBLK * D_DIM;
        {
            int dq   = (tid & 7) + ((tid >> 6) & 3) * 8;
            int kvpl = (tid >> 3) & 7;
            #pragma unroll
            for (int i = 0; i < 4; ++i) {
                int kvp = kvpl + i * 8;
                const float* s0 = vs + (2 * kvp) * D_DIM + dq * 4;
                float4 r0 = *(const float4*)s0;
                float4 r1 = *(const float4*)(s0 + D_DIM);
                #pragma unroll
                for (int wv = 0; wv < 4; ++wv) {
                    int d = dq * 4 + wv;
                    unsigned int pk = (unsigned int)f2bf(((const float*)&r0)[wv])
                                    | ((unsigned int)f2bf(((const float*)&r1)[wv]) << 16);
                    int idx = (d * 64 + 2 * kvp) ^ ((d & 7) << 3);
                    *(unsigned int*)&v_lds[idx] = pk;
                }
            }
        }
        __syncthreads();

        f32x4 sacc[4];
        #pragma unroll
        for (int ct = 0; ct < 4; ++ct) sacc[ct] = (f32x4){0.f, 0.f, 0.f, 0.f};
        #pragma unroll
        for (int kt = 0; kt < 4; ++kt) {
            #pragma unroll
            for (int ct = 0; ct < 4; ++ct) {
                int kv = ct * 16 + lr;
                int d0 = kt * 32 + g * 8;
                int idx = (kv * 128 + d0) ^ ((kv & 7) << 3);
                bf16x8 kf = *(const bf16x8*)&k_lds[idx];
                sacc[ct] = __builtin_amdgcn_mfma_f32_16x16x32_bf16(qf[kt], kf, sacc[ct], 0, 0, 0);
            }
        }

        float pv[4][4];
        float mt[4];
        #pragma unroll
        for (int r = 0; r < 4; ++r) mt[r] = -INFINITY;
        #pragma unroll
        for (int ct = 0; ct < 4; ++ct) {
            #pragma unroll
            for (int r = 0; r < 4; ++r) {
                float x = sacc[ct][r] * scale;
                x = (x == 0.0f) ? -1e9f : x;
                pv[ct][r] = x;
                mt[r] = fmaxf(mt[r], x);
            }
        }
        #pragma unroll
        for (int r = 0; r < 4; ++r) {
            #pragma unroll
            for (int msk = 1; msk <= 8; msk <<= 1)
                mt[r] = fmaxf(mt[r], __shfl_xor(mt[r], msk));
        }
        float corr[4], rs[4];
        #pragma unroll
        for (int r = 0; r < 4; ++r) {
            float mn = fmaxf(m[r], mt[r]);
            corr[r] = exp2f((m[r] - mn) * L2E);
            m[r] = mn;
            rs[r] = 0.f;
        }
        #pragma unroll
        for (int ct = 0; ct < 4; ++ct) {
            #pragma unroll
            for (int r = 0; r < 4; ++r) {
                float e = exp2f((pv[ct][r] - m[r]) * L2E);
                pv[ct][r] = e;
                rs[r] += e;
            }
        }
        #pragma unroll
        for (int r = 0; r < 4; ++r) {
            #pragma unroll
            for (int msk = 1; msk <= 8; msk <<= 1)
                rs[r] += __shfl_xor(rs[r], msk);
            lsum[r] = lsum[r] * corr[r] + rs[r];
        }
        #pragma unroll
        for (int dt = 0; dt < 8; ++dt) {
            #pragma unroll
            for (int r = 0; r < 4; ++r) o[dt][r] *= corr[r];
        }

        unsigned short* pw = p_lds + w * (16 * KBLK);
        #pragma unroll
        for (int ct = 0; ct < 4; ++ct) {
            #pragma unroll
            for (int r = 0; r < 4; ++r) {
                int qr = g * 4 + r;
                int kv = ct * 16 + lr;
                int idx = (qr * 64 + kv) ^ ((qr & 7) << 3);
                pw[idx] = f2bf(pv[ct][r]);
            }
        }

        #pragma unroll
        for (int kt2 = 0; kt2 < 2; ++kt2) {
            int kv0 = kt2 * 32 + g * 8;
            int idxp = (lr * 64 + kv0) ^ ((lr & 7) << 3);
            bf16x8 pa = *(const bf16x8*)&pw[idxp];
            #pragma unroll
            for (int dt = 0; dt < 8; ++dt) {
                int d = dt * 16 + lr;
                int idxv = (d * 64 + kv0) ^ ((d & 7) << 3);
                bf16x8 vb = *(const bf16x8*)&v_lds[idxv];
                o[dt] = __builtin_amdgcn_mfma_f32_16x16x32_bf16(pa, vb, o[dt], 0, 0, 0);
            }
        }
    }

    float* op = O + base + (size_t)qbase * D_DIM;
    #pragma unroll
    for (int r = 0; r < 4; ++r) {
        float inv = 1.0f / lsum[r];
        int row = w * 16 + g * 4 + r;
        #pragma unroll
        for (int dt = 0; dt < 8; ++dt) {
            op[row * D_DIM + dt * 16 + lr] = o[dt][r] * inv;
        }
    }
}

extern "C" void kernel_launch(void* const* d_in, const int* in_sizes, int n_in,
                              void* d_out, int out_size, void* d_ws, size_t ws_size,
                              hipStream_t stream) {
    const float* q = (const float*)d_in[0];
    const float* k = (const float*)d_in[1];
    const float* v = (const float*)d_in[2];
    float* out = (float*)d_out;

    const size_t nelem = (size_t)NBH * S_LEN * D_DIM;        // 16,777,216
    const size_t need  = 2 * nelem * sizeof(unsigned short); // 64 MiB

    if (ws_size >= need) {
        unsigned short* kbf = (unsigned short*)d_ws;
        unsigned short* vt  = kbf + nelem;
        hipLaunchKernelGGL(conv_k, dim3(2048), dim3(256), 0, stream, k, kbf);
        hipLaunchKernelGGL(conv_vt, dim3(NBH * 32 * 2), dim3(256), 0, stream, v, vt);
        hipLaunchKernelGGL(attn_fwd_bf, dim3(NBH * (S_LEN / QBLK)), dim3(256), 0, stream,
                           q, kbf, vt, out);
    } else {
        hipLaunchKernelGGL(attn_fwd_f32, dim3(NBH * (S_LEN / QBLK)), dim3(256), 0, stream,
                           q, k, v, out);
    }
}

// Round 3
// 242.647 us; speedup vs baseline: 1.9690x; 1.6520x over previous
//
#include <hip/hip_runtime.h>
#include <hip/hip_bf16.h>

#define S_LEN 2048
#define D_DIM 128
#define QBLK 128               // per block: 4 warps x 32 q-rows
#define KBLK 64
#define NSTEP (S_LEN / KBLK)   // 32
#define NBH 64                 // B*H

typedef __bf16 bf16x8 __attribute__((ext_vector_type(8)));
typedef float  f32x4  __attribute__((ext_vector_type(4)));
typedef float  f32x16 __attribute__((ext_vector_type(16)));
typedef unsigned short u16x8 __attribute__((ext_vector_type(8)));

union PkU { unsigned int u[4]; bf16x8 v; };
union QfU { u16x8 u; bf16x8 v; };

// RNE fp32 -> bf16 (bit pattern as ushort)
__device__ __forceinline__ unsigned short f2bf(float f) {
    unsigned int u = __float_as_uint(f);
    u += 0x7fffu + ((u >> 16) & 1u);
    return (unsigned short)(u >> 16);
}

__device__ __forceinline__ void gload_lds16(const void* g, void* l) {
    __builtin_amdgcn_global_load_lds(
        (const __attribute__((address_space(1))) unsigned int*)g,
        (__attribute__((address_space(3))) unsigned int*)l, 16, 0, 0);
}

__device__ __forceinline__ void block_sync() {
    asm volatile("" ::: "memory");
    __builtin_amdgcn_s_barrier();
    asm volatile("" ::: "memory");
}

// v_cvt_pk_bf16_f32: dst.lo16 = bf16(a), dst.hi16 = bf16(b)
__device__ __forceinline__ unsigned int cvtpk(float a, float b) {
    unsigned int r;
    asm("v_cvt_pk_bf16_f32 %0, %1, %2" : "=v"(r) : "v"(a), "v"(b));
    return r;
}

// v_permlane32_swap_b32 a, b:
//   new_a: lanes 0-31 keep a; lanes 32-63 get b from partner lane-32
//   new_b: lanes 0-31 get a from partner lane+32; lanes 32-63 keep b
__device__ __forceinline__ void pl32swap(unsigned int& a, unsigned int& b) {
    asm("v_permlane32_swap_b32 %0, %1" : "+v"(a), "+v"(b));
}

// ---------------- prepass: K fp32 -> bf16 (same layout) ----------------
__global__ __launch_bounds__(256)
void conv_k(const float* __restrict__ in, unsigned short* __restrict__ out) {
    const int n8 = (NBH * S_LEN * D_DIM) / 8;
    for (int c = blockIdx.x * blockDim.x + threadIdx.x; c < n8; c += gridDim.x * blockDim.x) {
        const float* s = in + (size_t)c * 8;
        float4 a = *(const float4*)s;
        float4 b = *(const float4*)(s + 4);
        u16x8 v;
        v[0] = f2bf(a.x); v[1] = f2bf(a.y); v[2] = f2bf(a.z); v[3] = f2bf(a.w);
        v[4] = f2bf(b.x); v[5] = f2bf(b.y); v[6] = f2bf(b.z); v[7] = f2bf(b.w);
        *(u16x8*)(out + (size_t)c * 8) = v;
    }
}

// ---------------- prepass: V fp32 [bh][s][d] -> bf16 transposed [bh][d][s] ----------------
__global__ __launch_bounds__(256)
void conv_vt(const float* __restrict__ V, unsigned short* __restrict__ Vt) {
    __shared__ unsigned short tl[64][72];
    const int b  = blockIdx.x;
    const int dt = b & 1;
    const int st = (b >> 1) & 31;
    const int bh = b >> 6;
    const float* src = V + (size_t)bh * S_LEN * D_DIM + (size_t)(st * 64) * D_DIM + dt * 64;
    #pragma unroll
    for (int i = 0; i < 4; ++i) {
        int c = threadIdx.x + i * 256;
        int r = c >> 4, c4 = c & 15;
        float4 x = *(const float4*)(src + r * D_DIM + c4 * 4);
        tl[r][c4 * 4 + 0] = f2bf(x.x);
        tl[r][c4 * 4 + 1] = f2bf(x.y);
        tl[r][c4 * 4 + 2] = f2bf(x.z);
        tl[r][c4 * 4 + 3] = f2bf(x.w);
    }
    __syncthreads();
    unsigned short* dst = Vt + (size_t)bh * D_DIM * S_LEN + (size_t)(dt * 64) * S_LEN + st * 64;
    #pragma unroll
    for (int i = 0; i < 2; ++i) {
        int c  = threadIdx.x + i * 256;
        int dl = c >> 3, s0 = (c & 7) * 8;
        u16x8 v;
        #pragma unroll
        for (int j = 0; j < 8; ++j) v[j] = tl[s0 + j][dl];
        *(u16x8*)(dst + (size_t)dl * S_LEN + s0) = v;
    }
}

// ---------------- main: swapped-QK^T 32x32, in-register softmax ----------------
__global__ __launch_bounds__(256, 2)
void attn_fwd_bf(const float* __restrict__ Q, const unsigned short* __restrict__ Kb,
                 const unsigned short* __restrict__ Vt, float* __restrict__ O) {
    // K dbuf 2x16KB + V dbuf 2x16KB = 64KB
    __shared__ unsigned short k_lds[2][KBLK * D_DIM];
    __shared__ unsigned short v_lds[2][D_DIM * KBLK];
    __shared__ float ls_sh[4][32];

    const int tid = threadIdx.x;
    const int w   = tid >> 6;       // wave 0..3
    const int l   = tid & 63;
    const int lo  = l & 31;
    const int hi  = l >> 5;

    // XCD-bijective swizzle (nwg=1024, 1024%8==0): head's 16 blocks share an XCD
    const int bid = blockIdx.x;
    const int swz = (bid & 7) * 128 + (bid >> 3);
    const int bh  = swz >> 4;       // 0..63
    const int qt  = swz & 15;       // 0..15
    const size_t base  = (size_t)bh * S_LEN * D_DIM;
    const int    qbase = qt * QBLK;

    const float scale = 0.08838834764831845f;   // 1/sqrt(128)
    const float L2E   = 1.4426950408889634f;

    // ---- staging source addresses (inverse-swizzled global, linear LDS dest) ----
    const char* kgp[4];
    const char* vgp[4];
    {
        const char* kB = (const char*)Kb + base * 2;
        const char* vB = (const char*)Vt + base * 2;
        #pragma unroll
        for (int i = 0; i < 4; ++i) {
            int c   = tid + i * 256;              // 0..1023, 16B chunks
            int kr  = c >> 4, kc8 = c & 15;       // K: row 0..63, col-chunk
            kgp[i] = kB + kr * (D_DIM * 2) + (((kc8 * 8) ^ ((kr & 7) << 3)) * 2);
            int vd  = c >> 3, vk8 = c & 7;        // V^T: d-row 0..127, kv-chunk
            vgp[i] = vB + (size_t)vd * (S_LEN * 2) + (((vk8 * 8) ^ ((vd & 7) << 3)) * 2);
        }
    }

    // ---- prologue: issue tile 0 ----
    #pragma unroll
    for (int i = 0; i < 4; ++i) {
        int c = tid + i * 256;
        gload_lds16(kgp[i], &k_lds[0][c * 8]);
        kgp[i] += KBLK * D_DIM * 2;
    }
    #pragma unroll
    for (int i = 0; i < 4; ++i) {
        int c = tid + i * 256;
        gload_lds16(vgp[i], &v_lds[0][c * 8]);
        vgp[i] += KBLK * 2;
    }

    // ---- Q fragments (scale folded in): qf[kt][j] = scale*Q[q=lo][16kt+8hi+j] ----
    bf16x8 qf[8];
    {
        const float* qp = Q + base + (size_t)(qbase + w * 32 + lo) * D_DIM + hi * 8;
        #pragma unroll
        for (int kt = 0; kt < 8; ++kt) {
            float4 a = *(const float4*)(qp + kt * 16);
            float4 b = *(const float4*)(qp + kt * 16 + 4);
            QfU t;
            t.u[0] = f2bf(a.x * scale); t.u[1] = f2bf(a.y * scale);
            t.u[2] = f2bf(a.z * scale); t.u[3] = f2bf(a.w * scale);
            t.u[4] = f2bf(b.x * scale); t.u[5] = f2bf(b.y * scale);
            t.u[6] = f2bf(b.z * scale); t.u[7] = f2bf(b.w * scale);
            qf[kt] = t.v;
        }
    }

    // ---- accumulators / softmax state ----
    f32x16 oo[4];
    #pragma unroll
    for (int dt = 0; dt < 4; ++dt)
        #pragma unroll
        for (int i = 0; i < 16; ++i) oo[dt][i] = 0.f;
    float mrow = -1e30f;
    float lsum = 0.f;

    #pragma unroll 1
    for (int t = 0; t < NSTEP; ++t) {
        const int cur = t & 1;
        if (t < NSTEP - 1) {
            #pragma unroll
            for (int i = 0; i < 4; ++i) {
                int c = tid + i * 256;
                gload_lds16(kgp[i], &k_lds[cur ^ 1][c * 8]);
                kgp[i] += KBLK * D_DIM * 2;
            }
            #pragma unroll
            for (int i = 0; i < 4; ++i) {
                int c = tid + i * 256;
                gload_lds16(vgp[i], &v_lds[cur ^ 1][c * 8]);
                vgp[i] += KBLK * 2;
            }
            asm volatile("s_waitcnt vmcnt(8)" ::: "memory");   // tile t landed
        } else {
            asm volatile("s_waitcnt vmcnt(0)" ::: "memory");
        }
        block_sync();

        // ---- S^T = K . Q^T : two 32x32 tiles over kv, K-dim = 128 ----
        const unsigned short* kb = k_lds[cur];
        f32x16 s0, s1;
        #pragma unroll
        for (int i = 0; i < 16; ++i) { s0[i] = 0.f; s1[i] = 0.f; }
        __builtin_amdgcn_s_setprio(1);
        #pragma unroll
        for (int kt = 0; kt < 8; ++kt) {
            int c = (16 * kt + 8 * hi) ^ ((lo & 7) << 3);
            bf16x8 kf0 = *(const bf16x8*)&kb[lo * 128 + c];
            s0 = __builtin_amdgcn_mfma_f32_32x32x16_bf16(kf0, qf[kt], s0, 0, 0, 0);
            bf16x8 kf1 = *(const bf16x8*)&kb[(32 + lo) * 128 + c];
            s1 = __builtin_amdgcn_mfma_f32_32x32x16_bf16(kf1, qf[kt], s1, 0, 0, 0);
        }
        __builtin_amdgcn_s_setprio(0);

        // ---- in-register softmax: lane holds P[q=lo][kv=crow(r,hi)], r=0..31 ----
        float p[32];
        #pragma unroll
        for (int i = 0; i < 16; ++i) { p[i] = s0[i]; p[16 + i] = s1[i]; }
        #pragma unroll
        for (int i = 0; i < 32; ++i) p[i] = (p[i] == 0.f) ? -1e9f : p[i];  // reference mask

        float tm[16];
        #pragma unroll
        for (int i = 0; i < 16; ++i) tm[i] = fmaxf(p[i], p[i + 16]);
        #pragma unroll
        for (int s = 8; s > 0; s >>= 1)
            #pragma unroll
            for (int i = 0; i < s; ++i) tm[i] = fmaxf(tm[i], tm[i + s]);
        float tmax = fmaxf(tm[0], __shfl_xor(tm[0], 32));

        // T13 defer-max: rescale only when tile max exceeds running max + 8
        if (!__all(tmax <= mrow + 8.0f)) {
            float mn   = fmaxf(mrow, tmax);
            float corr = exp2f((mrow - mn) * L2E);
            mrow = mn;
            lsum *= corr;
            #pragma unroll
            for (int dt = 0; dt < 4; ++dt) oo[dt] *= corr;
        }
        const float mL = mrow * L2E;
        #pragma unroll
        for (int i = 0; i < 32; ++i) p[i] = exp2f(__builtin_fmaf(p[i], L2E, -mL));

        float ts[16];
        #pragma unroll
        for (int i = 0; i < 16; ++i) ts[i] = p[i] + p[i + 16];
        #pragma unroll
        for (int s = 8; s > 0; s >>= 1)
            #pragma unroll
            for (int i = 0; i < s; ++i) ts[i] += ts[i + s];
        lsum += ts[0] + __shfl_xor(ts[0], 32);

        // ---- P -> bf16 A-fragments (T12: cvt_pk + permlane32_swap, no LDS) ----
        PkU pa[4];
        #pragma unroll
        for (int ks = 0; ks < 4; ++ks) {
            unsigned int a0 = cvtpk(p[8 * ks + 0], p[8 * ks + 1]);
            unsigned int b0 = cvtpk(p[8 * ks + 4], p[8 * ks + 5]);
            unsigned int a1 = cvtpk(p[8 * ks + 2], p[8 * ks + 3]);
            unsigned int b1 = cvtpk(p[8 * ks + 6], p[8 * ks + 7]);
            pl32swap(a0, b0);
            pl32swap(a1, b1);
            pa[ks].u[0] = a0; pa[ks].u[1] = a1; pa[ks].u[2] = b0; pa[ks].u[3] = b1;
        }

        // ---- O += P V : 4 d-tiles x 4 kv-slots ----
        const unsigned short* vb = v_lds[cur];
        __builtin_amdgcn_s_setprio(1);
        #pragma unroll
        for (int dt = 0; dt < 4; ++dt) {
            int d = dt * 32 + lo;
            #pragma unroll
            for (int ks = 0; ks < 4; ++ks) {
                int c = (16 * ks + 8 * hi) ^ ((lo & 7) << 3);   // d&7 == lo&7
                bf16x8 vf = *(const bf16x8*)&vb[d * 64 + c];
                oo[dt] = __builtin_amdgcn_mfma_f32_32x32x16_bf16(pa[ks].v, vf, oo[dt], 0, 0, 0);
            }
        }
        __builtin_amdgcn_s_setprio(0);

        block_sync();   // all reads of buf[cur] done before next-iter issue overwrites
    }

    // ---- epilogue: distribute 1/lsum across crow-mapped rows via LDS ----
    if (l < 32) ls_sh[w][lo] = 1.0f / lsum;
    __syncthreads();
    float* op = O + base + (size_t)(qbase + w * 32) * D_DIM + lo;
    #pragma unroll
    for (int r = 0; r < 16; ++r) {
        int q = (r & 3) + 8 * (r >> 2) + 4 * hi;
        float inv = ls_sh[w][q];
        #pragma unroll
        for (int dt = 0; dt < 4; ++dt) {
            op[q * D_DIM + dt * 32] = oo[dt][r] * inv;
        }
    }
}

// ---------------- fallback (round-1 kernel, fp32-staged, 16x16 path) ----------------
__global__ __launch_bounds__(256, 2)
void attn_fwd_f32(const float* __restrict__ Q, const float* __restrict__ K,
                  const float* __restrict__ V, float* __restrict__ O) {
    __shared__ unsigned short k_sh[64 * D_DIM];
    __shared__ unsigned short v_sh[D_DIM * 64];
    __shared__ unsigned short p_sh[4 * 16 * 64];

    const int tid = threadIdx.x;
    const int w   = tid >> 6;
    const int l   = tid & 63;
    const int g   = l >> 4;
    const int lr  = l & 15;

    const int bh    = blockIdx.x >> 5;
    const int qt    = blockIdx.x & 31;
    const size_t base  = (size_t)bh * S_LEN * D_DIM;
    const int    qbase = qt * 64;

    {
        const float* qp = Q + base + (size_t)qbase * D_DIM;
        #pragma unroll
        for (int i = 0; i < 4; ++i) {
            int c    = tid + i * 256;
            int row  = c >> 4;
            int col8 = c & 15;
            const float* src = qp + row * D_DIM + col8 * 8;
            float4 a = *(const float4*)src;
            float4 b = *(const float4*)(src + 4);
            unsigned short pk[8];
            pk[0] = f2bf(a.x); pk[1] = f2bf(a.y); pk[2] = f2bf(a.z); pk[3] = f2bf(a.w);
            pk[4] = f2bf(b.x); pk[5] = f2bf(b.y); pk[6] = f2bf(b.z); pk[7] = f2bf(b.w);
            int idx = (row * 128 + col8 * 8) ^ ((row & 7) << 3);
            #pragma unroll
            for (int j = 0; j < 8; ++j) k_sh[idx + j] = pk[j];
        }
    }
    __syncthreads();

    bf16x8 qf[4];
    {
        int row = w * 16 + lr;
        #pragma unroll
        for (int kt = 0; kt < 4; ++kt) {
            int d0 = kt * 32 + g * 8;
            int idx = (row * 128 + d0) ^ ((row & 7) << 3);
            qf[kt] = *(const bf16x8*)&k_sh[idx];
        }
    }

    f32x4 o[8];
    #pragma unroll
    for (int dt = 0; dt < 8; ++dt) o[dt] = (f32x4){0.f, 0.f, 0.f, 0.f};
    float m[4], lsum[4];
    #pragma unroll
    for (int r = 0; r < 4; ++r) { m[r] = -INFINITY; lsum[r] = 0.f; }

    const float* kp = K + base;
    const float* vp = V + base;
    const float  scale = 0.08838834764831845f;
    const float  L2E   = 1.4426950408889634f;

    for (int t = 0; t < NSTEP; ++t) {
        __syncthreads();

        const float* ks = kp + (size_t)t * 64 * D_DIM;
        #pragma unroll
        for (int i = 0; i < 4; ++i) {
            int c    = tid + i * 256;
            int row  = c >> 4;
            int col8 = c & 15;
            const float* src = ks + row * D_DIM + col8 * 8;
            float4 a = *(const float4*)src;
            float4 b = *(const float4*)(src + 4);
            unsigned short pk[8];
            pk[0] = f2bf(a.x); pk[1] = f2bf(a.y); pk[2] = f2bf(a.z); pk[3] = f2bf(a.w);
            pk[4] = f2bf(b.x); pk[5] = f2bf(b.y); pk[6] = f2bf(b.z); pk[7] = f2bf(b.w);
            int idx = (row * 128 + col8 * 8) ^ ((row & 7) << 3);
            #pragma unroll
            for (int j = 0; j < 8; ++j) k_sh[idx + j] = pk[j];
        }

        const float* vs = vp + (size_t)t * 64 * D_DIM;
        {
            int dq   = (tid & 7) + ((tid >> 6) & 3) * 8;
            int kvpl = (tid >> 3) & 7;
            #pragma unroll
            for (int i = 0; i < 4; ++i) {
                int kvp = kvpl + i * 8;
                const float* s0 = vs + (2 * kvp) * D_DIM + dq * 4;
                float4 r0 = *(const float4*)s0;
                float4 r1 = *(const float4*)(s0 + D_DIM);
                #pragma unroll
                for (int wv = 0; wv < 4; ++wv) {
                    int d = dq * 4 + wv;
                    unsigned int pk = (unsigned int)f2bf(((const float*)&r0)[wv])
                                    | ((unsigned int)f2bf(((const float*)&r1)[wv]) << 16);
                    int idx = (d * 64 + 2 * kvp) ^ ((d & 7) << 3);
                    *(unsigned int*)&v_sh[idx] = pk;
                }
            }
        }
        __syncthreads();

        f32x4 sacc[4];
        #pragma unroll
        for (int ct = 0; ct < 4; ++ct) sacc[ct] = (f32x4){0.f, 0.f, 0.f, 0.f};
        #pragma unroll
        for (int kt = 0; kt < 4; ++kt) {
            #pragma unroll
            for (int ct = 0; ct < 4; ++ct) {
                int kv = ct * 16 + lr;
                int d0 = kt * 32 + g * 8;
                int idx = (kv * 128 + d0) ^ ((kv & 7) << 3);
                bf16x8 kf = *(const bf16x8*)&k_sh[idx];
                sacc[ct] = __builtin_amdgcn_mfma_f32_16x16x32_bf16(qf[kt], kf, sacc[ct], 0, 0, 0);
            }
        }

        float pv[4][4];
        float mt[4];
        #pragma unroll
        for (int r = 0; r < 4; ++r) mt[r] = -INFINITY;
        #pragma unroll
        for (int ct = 0; ct < 4; ++ct) {
            #pragma unroll
            for (int r = 0; r < 4; ++r) {
                float x = sacc[ct][r] * scale;
                x = (x == 0.0f) ? -1e9f : x;
                pv[ct][r] = x;
                mt[r] = fmaxf(mt[r], x);
            }
        }
        #pragma unroll
        for (int r = 0; r < 4; ++r) {
            #pragma unroll
            for (int msk = 1; msk <= 8; msk <<= 1)
                mt[r] = fmaxf(mt[r], __shfl_xor(mt[r], msk));
        }
        float corr[4], rs[4];
        #pragma unroll
        for (int r = 0; r < 4; ++r) {
            float mn = fmaxf(m[r], mt[r]);
            corr[r] = exp2f((m[r] - mn) * L2E);
            m[r] = mn;
            rs[r] = 0.f;
        }
        #pragma unroll
        for (int ct = 0; ct < 4; ++ct) {
            #pragma unroll
            for (int r = 0; r < 4; ++r) {
                float e = exp2f((pv[ct][r] - m[r]) * L2E);
                pv[ct][r] = e;
                rs[r] += e;
            }
        }
        #pragma unroll
        for (int r = 0; r < 4; ++r) {
            #pragma unroll
            for (int msk = 1; msk <= 8; msk <<= 1)
                rs[r] += __shfl_xor(rs[r], msk);
            lsum[r] = lsum[r] * corr[r] + rs[r];
        }
        #pragma unroll
        for (int dt = 0; dt < 8; ++dt) {
            #pragma unroll
            for (int r = 0; r < 4; ++r) o[dt][r] *= corr[r];
        }

        unsigned short* pw = p_sh + w * (16 * 64);
        #pragma unroll
        for (int ct = 0; ct < 4; ++ct) {
            #pragma unroll
            for (int r = 0; r < 4; ++r) {
                int qr = g * 4 + r;
                int kv = ct * 16 + lr;
                int idx = (qr * 64 + kv) ^ ((qr & 7) << 3);
                pw[idx] = f2bf(pv[ct][r]);
            }
        }

        #pragma unroll
        for (int kt2 = 0; kt2 < 2; ++kt2) {
            int kv0 = kt2 * 32 + g * 8;
            int idxp = (lr * 64 + kv0) ^ ((lr & 7) << 3);
            bf16x8 pa = *(const bf16x8*)&pw[idxp];
            #pragma unroll
            for (int dt = 0; dt < 8; ++dt) {
                int d = dt * 16 + lr;
                int idxv = (d * 64 + kv0) ^ ((d & 7) << 3);
                bf16x8 vb = *(const bf16x8*)&v_sh[idxv];
                o[dt] = __builtin_amdgcn_mfma_f32_16x16x32_bf16(pa, vb, o[dt], 0, 0, 0);
            }
        }
    }

    float* op = O + base + (size_t)qbase * D_DIM;
    #pragma unroll
    for (int r = 0; r < 4; ++r) {
        float inv = 1.0f / lsum[r];
        int row = w * 16 + g * 4 + r;
        #pragma unroll
        for (int dt = 0; dt < 8; ++dt) {
            op[row * D_DIM + dt * 16 + lr] = o[dt][r] * inv;
        }
    }
}

extern "C" void kernel_launch(void* const* d_in, const int* in_sizes, int n_in,
                              void* d_out, int out_size, void* d_ws, size_t ws_size,
                              hipStream_t stream) {
    const float* q = (const float*)d_in[0];
    const float* k = (const float*)d_in[1];
    const float* v = (const float*)d_in[2];
    float* out = (float*)d_out;

    const size_t nelem = (size_t)NBH * S_LEN * D_DIM;        // 16,777,216
    const size_t need  = 2 * nelem * sizeof(unsigned short); // 64 MiB

    if (ws_size >= need) {
        unsigned short* kbf = (unsigned short*)d_ws;
        unsigned short* vt  = kbf + nelem;
        hipLaunchKernelGGL(conv_k, dim3(2048), dim3(256), 0, stream, k, kbf);
        hipLaunchKernelGGL(conv_vt, dim3(NBH * 32 * 2), dim3(256), 0, stream, v, vt);
        hipLaunchKernelGGL(attn_fwd_bf, dim3(NBH * (S_LEN / QBLK)), dim3(256), 0, stream,
                           q, kbf, vt, out);
    } else {
        hipLaunchKernelGGL(attn_fwd_f32, dim3(NBH * 32), dim3(256), 0, stream,
                           q, k, v, out);
    }
}